// Round 7
// baseline (202.495 us; speedup 1.0000x reference)
//
#include <hip/hip_runtime.h>
#include <stdint.h>

// Problem constants: B=2, S=2048, HIDDEN=1024, NH=16, D=64
// M = B*S = 4096, N1 = 3072, K = 1024, N2 = 1024, BH = 32

#define DEV static __device__ __forceinline__

typedef unsigned short u16;
typedef __attribute__((ext_vector_type(4))) float f32x4;
typedef __attribute__((ext_vector_type(16))) float f32x16;
typedef __bf16 bf16x8 __attribute__((ext_vector_type(8)));
typedef __attribute__((ext_vector_type(8))) unsigned short u16x8;
typedef __attribute__((ext_vector_type(4))) unsigned short u16x4;

// 0.125 * log2(e): folded into Q so softmax weights are exp2(acc)
#define QSCALE 0.18033688011112042f

DEV u16 f2bf(float f) {
    unsigned u = __builtin_bit_cast(unsigned, f);
    u += 0x7fffu + ((u >> 16) & 1u);
    return (u16)(u >> 16);
}
DEV float bf2f(u16 h) {
    unsigned u = ((unsigned)h) << 16;
    return __builtin_bit_cast(float, u);
}

// async global->LDS, 16B per lane. LDS dest must be wave-uniform base + lane*16.
DEV void async_copy16(const void* g, void* l) {
    __builtin_amdgcn_global_load_lds(
        (__attribute__((address_space(1))) void*)(g),
        (__attribute__((address_space(3))) void*)(l), 16, 0, 0);
}

// ---------------- fused prep: cast x + transpose both weights ----------------
// grid sections: [0,4096) cast x; [4096,7168) transpose wqkv (96x32);
// [7168,8192) transpose wo (32x32). One launch instead of three.
__global__ __launch_bounds__(256) void prep(
    const float* __restrict__ x, u16* __restrict__ xb,
    const float* __restrict__ wqkv, u16* __restrict__ wqkvT,
    const float* __restrict__ wo, u16* __restrict__ woT) {
    __shared__ float tile[32][33];
    const int bid = blockIdx.x;
    const int t = threadIdx.x;
    if (bid < 4096) {
        int i = bid * 256 + t;
        f32x4 v = *(const f32x4*)(x + (size_t)i * 4);
        u16x4 o;
#pragma unroll
        for (int j = 0; j < 4; j++) o[j] = f2bf(v[j]);
        *(u16x4*)(xb + (size_t)i * 4) = o;
        return;
    }
    const float* src;
    u16* dst;
    int rows, cols, c0, r0;
    if (bid < 7168) {
        int b2 = bid - 4096;
        src = wqkv; dst = wqkvT; rows = 1024; cols = 3072;
        c0 = (b2 % 96) * 32; r0 = (b2 / 96) * 32;
    } else {
        int b3 = bid - 7168;
        src = wo; dst = woT; rows = 1024; cols = 1024;
        c0 = (b3 % 32) * 32; r0 = (b3 / 32) * 32;
    }
    int tx = t & 31, ty = t >> 5;   // (32,8)
#pragma unroll
    for (int i = 0; i < 4; i++)
        tile[ty + i * 8][tx] = src[(size_t)(r0 + ty + i * 8) * cols + c0 + tx];
    __syncthreads();
#pragma unroll
    for (int i = 0; i < 4; i++)
        dst[(size_t)(c0 + ty + i * 8) * rows + r0 + tx] = f2bf(tile[tx][ty + i * 8]);
}

// ---------------- GEMM1: qkv projection ----------------
// 128x128 tile; LDS-transpose epilogue -> coalesced 16B stores into
// q/k/v [bh][s][d] bf16. n-range of each block lies in exactly one of
// q/k/v (n0 multiple of 128, sections are 1024-wide), so dst/scale are
// block-uniform.
__global__ __launch_bounds__(256) void gemm_qkv(
    const u16* __restrict__ A, const u16* __restrict__ Bt,
    u16* __restrict__ qb, u16* __restrict__ kb, u16* __restrict__ vb) {
    __shared__ __align__(16) u16 smem[128 * 136];  // 34 KB; aliases As/Bs/Cs
    u16* As = smem;            // [128][32]
    u16* Bs = smem + 4096;     // [128][32]
    const int t = threadIdx.x;
    const int wave = t >> 6;
    const int lane = t & 63;
    const int quad = lane >> 4;
    const int l16 = lane & 15;
    const int wr = wave >> 1;
    const int wc = wave & 1;
    const int m0 = blockIdx.y * 128;
    const int n0 = blockIdx.x * 128;

    f32x4 acc[4][4];
#pragma unroll
    for (int i = 0; i < 4; i++)
#pragma unroll
        for (int j = 0; j < 4; j++) acc[i][j] = {0.f, 0.f, 0.f, 0.f};

    for (int kt = 0; kt < 1024; kt += 32) {
#pragma unroll
        for (int i = 0; i < 2; i++) {
            int idx = i * 256 + t;
            int row = idx >> 2, kc = idx & 3;
            async_copy16(A + (size_t)(m0 + row) * 1024 + kt + kc * 8, &As[idx * 8]);
            async_copy16(Bt + (size_t)(n0 + row) * 1024 + kt + kc * 8, &Bs[idx * 8]);
        }
        __syncthreads();
        bf16x8 af[4], bfr[4];
#pragma unroll
        for (int mt = 0; mt < 4; mt++)
            af[mt] = *(const bf16x8*)&As[(wr * 64 + mt * 16 + l16) * 32 + quad * 8];
#pragma unroll
        for (int nt = 0; nt < 4; nt++)
            bfr[nt] = *(const bf16x8*)&Bs[(wc * 64 + nt * 16 + l16) * 32 + quad * 8];
#pragma unroll
        for (int mt = 0; mt < 4; mt++)
#pragma unroll
            for (int nt = 0; nt < 4; nt++)
                acc[mt][nt] = __builtin_amdgcn_mfma_f32_16x16x32_bf16(
                    af[mt], bfr[nt], acc[mt][nt], 0, 0, 0);
        __syncthreads();
    }

    // ---- epilogue: acc -> LDS [m][n] bf16 (stride 136) -> coalesced global
    const int tsel = n0 >> 10;  // 0=q 1=k 2=v (block-uniform)
    u16* dst = tsel == 0 ? qb : (tsel == 1 ? kb : vb);
    const float scl = tsel == 0 ? QSCALE : 1.0f;
#pragma unroll
    for (int mt = 0; mt < 4; mt++)
#pragma unroll
        for (int nt = 0; nt < 4; nt++) {
            int nn = wc * 64 + nt * 16 + l16;
#pragma unroll
            for (int r = 0; r < 4; r++) {
                int mm = wr * 64 + mt * 16 + quad * 4 + r;
                smem[mm * 136 + nn] = f2bf(acc[mt][nt][r] * scl);
            }
        }
    __syncthreads();
    const int col0 = (l16) * 8;       // 0..120, within one 64-d head (8-aligned)
    const int rowb = (t >> 4);        // 0..15
    const int h0 = (n0 & 1023) >> 6;  // first of the block's 2 heads
#pragma unroll
    for (int i = 0; i < 8; i++) {
        int row = i * 16 + rowb;      // 0..127
        u16x8 v = *(const u16x8*)&smem[row * 136 + col0];
        int h = h0 + (col0 >> 6), d = col0 & 63;
        int mm = m0 + row;
        int b = mm >> 11, s = mm & 2047;
        *(u16x8*)&dst[((size_t)((b * 16 + h) * 2048 + s)) * 64 + d] = v;
    }
}

// GEMM2 (fused with scale_v): out = (csum .* v) @ w_o, fp32 output.
// A-tile reg-staged from vb with on-the-fly colsum scaling (identical
// rounding to the old scale_v: fp32 mul then f2bf). B via global_load_lds.
// 64x128 tiles -> 512 blocks (2/CU).
__global__ __launch_bounds__(256) void gemm_out(
    const u16* __restrict__ vb, const float* __restrict__ csum,
    const u16* __restrict__ Bt, float* __restrict__ out) {
    __shared__ __align__(16) u16 As[64 * 32];
    __shared__ __align__(16) u16 Bs[128 * 32];
    const int m0 = blockIdx.y * 64;
    const int n0 = blockIdx.x * 128;
    const int t = threadIdx.x;
    const int wave = t >> 6, lane = t & 63;
    const int quad = lane >> 4, l16 = lane & 15;
    const int wr = wave >> 1, wc = wave & 1;  // wave tile: 32 rows x 64 cols

    // fixed per-thread A coords: row m (b,s), col block (t&3)*8 within K-step
    const int arow = m0 + (t >> 2);
    const int ab = arow >> 11, as = arow & 2047;

    f32x4 acc[2][4];
#pragma unroll
    for (int i = 0; i < 2; i++)
#pragma unroll
        for (int j = 0; j < 4; j++) acc[i][j] = {0.f, 0.f, 0.f, 0.f};

    for (int kt = 0; kt < 1024; kt += 32) {
        {   // A: load vb, scale by csum[bh][s], write LDS
            int c = kt + (t & 3) * 8;          // col in [0,1024), 8-aligned
            int h = c >> 6, d0 = c & 63;
            int bh = ab * 16 + h;
            float cs = csum[bh * 2048 + as];
            u16x8 v = *(const u16x8*)&vb[((size_t)(bh * 2048 + as)) * 64 + d0];
            u16x8 o;
#pragma unroll
            for (int i = 0; i < 8; i++) o[i] = f2bf(bf2f(v[i]) * cs);
            *(u16x8*)&As[t * 8] = o;
        }
#pragma unroll
        for (int i = 0; i < 2; i++) {
            int idx = i * 256 + t;
            int row = idx >> 2, kc = idx & 3;
            async_copy16(Bt + (size_t)(n0 + row) * 1024 + kt + kc * 8, &Bs[idx * 8]);
        }
        __syncthreads();
        bf16x8 af[2], bfr[4];
#pragma unroll
        for (int mt = 0; mt < 2; mt++)
            af[mt] = *(const bf16x8*)&As[(wr * 32 + mt * 16 + l16) * 32 + quad * 8];
#pragma unroll
        for (int nt = 0; nt < 4; nt++)
            bfr[nt] = *(const bf16x8*)&Bs[(wc * 64 + nt * 16 + l16) * 32 + quad * 8];
#pragma unroll
        for (int mt = 0; mt < 2; mt++)
#pragma unroll
            for (int nt = 0; nt < 4; nt++)
                acc[mt][nt] = __builtin_amdgcn_mfma_f32_16x16x32_bf16(
                    af[mt], bfr[nt], acc[mt][nt], 0, 0, 0);
        __syncthreads();
    }
#pragma unroll
    for (int nt = 0; nt < 4; nt++) {
        int nn = n0 + wc * 64 + nt * 16 + l16;
#pragma unroll
        for (int mt = 0; mt < 2; mt++) {
#pragma unroll
            for (int r = 0; r < 4; r++) {
                int mm = m0 + wr * 32 + mt * 16 + quad * 4 + r;
                out[(size_t)mm * 1024 + nn] = acc[mt][nt][r];
            }
        }
    }
}

// ---------------- attention passes (R6 structure, unchanged) ---------------
// No max subtraction: scores are O(+-5); exp(s)/sum(exp(s)) == softmax.
// Q pre-scaled by 0.125*log2e so weights are exp2(acc).
// 32x32x16 layouts: A/B [row=lane&31][k=f*16+(lane>>5)*8+j];
// C/D col=lane&31, row=(r&3)+8*(r>>2)+4*(lane>>5).
// Counted-vmcnt double-buffer pipeline (R6): STAGE(t+1) issued last, then
// fused "s_waitcnt vmcnt(4); s_barrier" -> tile t landed, t+1 in flight.

#define WAITBAR_4 asm volatile("s_waitcnt vmcnt(4)\n\ts_barrier" ::: "memory")
#define WAITBAR_0 asm volatile("s_waitcnt vmcnt(0)\n\ts_barrier" ::: "memory")
#define BAR_ONLY  asm volatile("s_barrier" ::: "memory")

// Pass 1: block = 4 waves x 64 q-rows = 256 q-rows; k-chunk = 512 rows,
// staged as 4 tiles of 128 (XOR-swizzled, double-buffered). lp: 4 partials.
__global__ __launch_bounds__(256) void attn_pass1(
    const u16* __restrict__ qb, const u16* __restrict__ kb,
    float* __restrict__ lp) {
    __shared__ __align__(16) u16 Ks[2][128 * 64];  // 2 x 16 KB, XOR-swizzled
    const int t = threadIdx.x;
    const int wave = t >> 6;
    const int lane = t & 63;
    const int l32 = lane & 31, half = lane >> 5;
    const int kchunk = blockIdx.x & 3;        // 512 k-rows each
    const int qblk = (blockIdx.x >> 2) & 7;   // 256 q-rows each
    const int bh = blockIdx.x >> 5;
    const int q0 = qblk * 256 + wave * 64;

    // persistent Q fragments, 2 q-sets: A[m=l32][k=f*16+half*8+j]
    bf16x8 a[2][4];
#pragma unroll
    for (int qs = 0; qs < 2; qs++) {
        const u16* Qr = qb + (size_t)(bh * 2048 + q0 + qs * 32 + l32) * 64 + half * 8;
#pragma unroll
        for (int f = 0; f < 4; f++) a[qs][f] = *(const bf16x8*)&Qr[f * 16];
    }

    const u16* Kbase = kb + (size_t)(bh * 2048 + kchunk * 512) * 64;

    float lsum[2][16];
#pragma unroll
    for (int qs = 0; qs < 2; qs++)
#pragma unroll
        for (int r = 0; r < 16; r++) lsum[qs][r] = 0.f;

    f32x16 ZZ;
#pragma unroll
    for (int r = 0; r < 16; r++) ZZ[r] = 0.f;

    // STAGE one 128-row tile: LDS[row][blk] = G[row][blk ^ (row&7)]
#define STAGE_K(buf, kt)                                                        \
    {                                                                           \
        _Pragma("unroll") for (int i = 0; i < 4; i++) {                         \
            int idx = i * 256 + t;                                              \
            int row = idx >> 3;                                                 \
            int blk = (idx & 7) ^ (row & 7);                                    \
            async_copy16(Kbase + (size_t)((kt) * 128 + row) * 64 + blk * 8,     \
                         &Ks[buf][idx * 8]);                                    \
        }                                                                       \
    }

#define COMPUTE_K(cur)                                                          \
    {                                                                           \
        _Pragma("unroll") for (int sub = 0; sub < 4; sub++) {                   \
            const int row = sub * 32 + l32;                                     \
            const int r7 = row & 7;                                             \
            bf16x8 bfr[4];                                                      \
            _Pragma("unroll") for (int f = 0; f < 4; f++)                       \
                bfr[f] = *(const bf16x8*)&Ks[cur][row * 64 +                    \
                                                 (((f * 2 + half)) ^ r7) * 8];  \
            __builtin_amdgcn_s_setprio(1);                                      \
            _Pragma("unroll") for (int qs = 0; qs < 2; qs++) {                  \
                f32x16 acc = __builtin_amdgcn_mfma_f32_32x32x16_bf16(           \
                    a[qs][0], bfr[0], ZZ, 0, 0, 0);                             \
                _Pragma("unroll") for (int f = 1; f < 4; f++)                   \
                    acc = __builtin_amdgcn_mfma_f32_32x32x16_bf16(              \
                        a[qs][f], bfr[f], acc, 0, 0, 0);                        \
                __builtin_amdgcn_s_setprio(0);                                  \
                _Pragma("unroll") for (int r = 0; r < 16; r++)                  \
                    lsum[qs][r] += __builtin_amdgcn_exp2f(acc[r]);              \
                __builtin_amdgcn_s_setprio(1);                                  \
            }                                                                   \
            __builtin_amdgcn_s_setprio(0);                                     \
        }                                                                       \
    }

    STAGE_K(0, 0);
    for (int kt = 0; kt < 3; kt++) {   // rolled: small code, low VGPR
        const int cur = kt & 1;
        STAGE_K(cur ^ 1, kt + 1);      // last vmem issued before the wait
        WAITBAR_4;                     // tile kt landed; kt+1 in flight
        COMPUTE_K(cur);
        BAR_ONLY;                      // Ks[cur] reads done -> reusable
    }
    WAITBAR_0;                         // peeled last tile (3) in buf 1
    COMPUTE_K(1);

    // reduce each row across the 32 k-columns (lanes within each half)
#pragma unroll
    for (int qs = 0; qs < 2; qs++) {
#pragma unroll
        for (int r = 0; r < 16; r++) {
            float v = lsum[qs][r];
            v += __shfl_xor(v, 1);
            v += __shfl_xor(v, 2);
            v += __shfl_xor(v, 4);
            v += __shfl_xor(v, 8);
            v += __shfl_xor(v, 16);
            lsum[qs][r] = v;
        }
    }
    if (l32 == 0) {
#pragma unroll
        for (int qs = 0; qs < 2; qs++) {
            float* dst = lp + kchunk * 65536 + bh * 2048 + q0 + qs * 32 + half * 4;
#pragma unroll
            for (int r = 0; r < 16; r++)
                dst[(r & 3) + 8 * (r >> 2)] = lsum[qs][r];
        }
    }
}

// Pass 2: block = 4 waves x 64 k-cols = 256 k-cols; q-chunk = 512 rows,
// staged as 4 tiles of 128; li = 1/(sum of 4 lp partials) in LDS.
// Colsum accumulated into csum via atomicAdd (csum zeroed by memsetAsync).
__global__ __launch_bounds__(256) void attn_pass2(
    const u16* __restrict__ qb, const u16* __restrict__ kb,
    const float* __restrict__ lp, float* __restrict__ csum) {
    __shared__ __align__(16) u16 Qs[2][128 * 64];  // 2 x 16 KB, XOR-swizzled
    __shared__ __align__(16) float li_lds[512];
    const int t = threadIdx.x;
    const int wave = t >> 6;
    const int lane = t & 63;
    const int l32 = lane & 31, half = lane >> 5;
    const int qchunk = blockIdx.x & 3;        // 512 q-rows each
    const int kblk = (blockIdx.x >> 2) & 7;   // 256 k-cols each
    const int bh = blockIdx.x >> 5;
    const int k0 = kblk * 256 + wave * 64;

    // li table for this block's 512 q-rows
    {
        const int base = bh * 2048 + qchunk * 512;
#pragma unroll
        for (int i = 0; i < 2; i++) {
            int q = i * 256 + t;
            float s = lp[base + q] + lp[65536 + base + q] + lp[131072 + base + q] +
                      lp[196608 + base + q];
            li_lds[q] = 1.0f / s;
        }
    }

    // persistent K fragments, 2 k-sets: B[n=l32][k=f*16+half*8+j]
    bf16x8 b[2][4];
#pragma unroll
    for (int ks = 0; ks < 2; ks++) {
        const u16* Kr = kb + (size_t)(bh * 2048 + k0 + ks * 32 + l32) * 64 + half * 8;
#pragma unroll
        for (int f = 0; f < 4; f++) b[ks][f] = *(const bf16x8*)&Kr[f * 16];
    }

    const u16* Qbase = qb + (size_t)(bh * 2048 + qchunk * 512) * 64;

    f32x16 ZZ;
#pragma unroll
    for (int r = 0; r < 16; r++) ZZ[r] = 0.f;

#define STAGE_Q(buf, qt)                                                        \
    {                                                                           \
        _Pragma("unroll") for (int i = 0; i < 4; i++) {                         \
            int idx = i * 256 + t;                                              \
            int row = idx >> 3;                                                 \
            int blk = (idx & 7) ^ (row & 7);                                    \
            async_copy16(Qbase + (size_t)((qt) * 128 + row) * 64 + blk * 8,     \
                         &Qs[buf][idx * 8]);                                    \
        }                                                                       \
    }

#define COMPUTE_Q(cur, qt)                                                      \
    {                                                                           \
        _Pragma("unroll") for (int sub = 0; sub < 4; sub++) {                   \
            const int row = sub * 32 + l32;                                     \
            const int r7 = row & 7;                                             \
            bf16x8 af[4];                                                       \
            _Pragma("unroll") for (int f = 0; f < 4; f++)                       \
                af[f] = *(const bf16x8*)&Qs[cur][row * 64 +                     \
                                                 (((f * 2 + half)) ^ r7) * 8];  \
            const float* lr = &li_lds[(qt) * 128 + sub * 32 + half * 4];        \
            f32x4 li0 = *(const f32x4*)&lr[0];                                  \
            f32x4 li1 = *(const f32x4*)&lr[8];                                  \
            f32x4 li2 = *(const f32x4*)&lr[16];                                 \
            f32x4 li3 = *(const f32x4*)&lr[24];                                 \
            __builtin_amdgcn_s_setprio(1);                                      \
            _Pragma("unroll") for (int ks = 0; ks < 2; ks++) {                  \
                f32x16 acc = __builtin_amdgcn_mfma_f32_32x32x16_bf16(           \
                    af[0], b[ks][0], ZZ, 0, 0, 0);                              \
                _Pragma("unroll") for (int f = 1; f < 4; f++)                   \
                    acc = __builtin_amdgcn_mfma_f32_32x32x16_bf16(              \
                        af[f], b[ks][f], acc, 0, 0, 0);                         \
                __builtin_amdgcn_s_setprio(0);                                  \
                float c = cs[ks];                                               \
                _Pragma("unroll") for (int r = 0; r < 4; r++)                   \
                    c += __builtin_amdgcn_exp2f(acc[r]) * li0[r];               \
                _Pragma("unroll") for (int r = 0; r < 4; r++)                   \
                    c += __builtin_amdgcn_exp2f(acc[4 + r]) * li1[r];           \
                _Pragma("unroll") for (int r = 0; r < 4; r++)                   \
                    c += __builtin_amdgcn_exp2f(acc[8 + r]) * li2[r];           \
                _Pragma("unroll") for (int r = 0; r < 4; r++)                   \
                    c += __builtin_amdgcn_exp2f(acc[12 + r]) * li3[r];          \
                cs[ks] = c;                                                     \
                __builtin_amdgcn_s_setprio(1);                                  \
            }                                                                   \
            __builtin_amdgcn_s_setprio(0);                                     \
        }                                                                       \
    }

    float cs[2] = {0.f, 0.f};
    __syncthreads();      // li_lds visible (drains only lp loads; no STAGE yet)
    STAGE_Q(0, 0);

    for (int qt = 0; qt < 3; qt++) {   // rolled
        const int cur = qt & 1;
        STAGE_Q(cur ^ 1, qt + 1);      // last vmem issued before the wait
        WAITBAR_4;                     // tile qt landed; qt+1 in flight
        COMPUTE_Q(cur, qt);
        BAR_ONLY;                      // Qs[cur] reads done -> reusable
    }
    WAITBAR_0;                         // peeled last tile (3) in buf 1
    COMPUTE_Q(1, 3);

#pragma unroll
    for (int ks = 0; ks < 2; ks++) {
        float v = cs[ks] + __shfl_xor(cs[ks], 32);
        if (lane < 32)
            atomicAdd(&csum[bh * 2048 + k0 + ks * 32 + lane], v);
    }
}

// ---------------- launch ----------------

extern "C" void kernel_launch(void* const* d_in, const int* in_sizes, int n_in,
                              void* d_out, int out_size, void* d_ws, size_t ws_size,
                              hipStream_t stream) {
    const float* x    = (const float*)d_in[0];   // [2,2048,1024]
    const float* wqkv = (const float*)d_in[1];   // [1024,3072]
    const float* wo   = (const float*)d_in[2];   // [1024,1024]
    float* out = (float*)d_out;                  // [2,2048,1024] fp32
    char* ws = (char*)d_ws;

    u16* xb      = (u16*)(ws);                   // [4096][1024] bf16 (dead after gemm_qkv)
    u16* wqkvT   = (u16*)(ws + 8388608);         // [3072][1024] bf16
    u16* woT     = (u16*)(ws + 14680064);        // [1024][1024] bf16
    u16* qb      = (u16*)(ws + 16777216);        // [32][2048][64] bf16
    u16* kb      = (u16*)(ws + 25165824);
    u16* vb      = (u16*)(ws + 33554432);
    // partial buffers alias xb (dead after gemm_qkv)
    float* lp    = (float*)(ws);                 // [4][32][2048]
    float* csum  = (float*)(ws + 1048576);       // [32][2048] summed colsum

    prep<<<8192, 256, 0, stream>>>(x, xb, wqkv, wqkvT, wo, woT);
    gemm_qkv<<<dim3(24, 32), 256, 0, stream>>>(xb, wqkvT, qb, kb, vb);
    hipMemsetAsync(csum, 0, 262144, stream);
    attn_pass1<<<1024, 256, 0, stream>>>(qb, kb, lp);
    attn_pass2<<<1024, 256, 0, stream>>>(qb, kb, lp, csum);
    gemm_out<<<dim3(8, 64), 256, 0, stream>>>(vb, csum, woT, out);
}

// Round 8
// 199.704 us; speedup vs baseline: 1.0140x; 1.0140x over previous
//
#include <hip/hip_runtime.h>
#include <stdint.h>

// Problem constants: B=2, S=2048, HIDDEN=1024, NH=16, D=64
// M = B*S = 4096, N1 = 3072, K = 1024, N2 = 1024, BH = 32

#define DEV static __device__ __forceinline__

typedef unsigned short u16;
typedef __attribute__((ext_vector_type(4))) float f32x4;
typedef __attribute__((ext_vector_type(16))) float f32x16;
typedef __bf16 bf16x8 __attribute__((ext_vector_type(8)));
typedef __attribute__((ext_vector_type(8))) unsigned short u16x8;
typedef __attribute__((ext_vector_type(4))) unsigned short u16x4;

// 0.125 * log2(e): folded into Q so softmax weights are exp2(acc)
#define QSCALE 0.18033688011112042f

DEV u16 f2bf(float f) {
    unsigned u = __builtin_bit_cast(unsigned, f);
    u += 0x7fffu + ((u >> 16) & 1u);
    return (u16)(u >> 16);
}
DEV float bf2f(u16 h) {
    unsigned u = ((unsigned)h) << 16;
    return __builtin_bit_cast(float, u);
}

// async global->LDS, 16B per lane. LDS dest must be wave-uniform base + lane*16.
DEV void async_copy16(const void* g, void* l) {
    __builtin_amdgcn_global_load_lds(
        (__attribute__((address_space(1))) void*)(g),
        (__attribute__((address_space(3))) void*)(l), 16, 0, 0);
}

// counted-vmcnt barrier pair (validated R6): STAGE(next) is the last vmem
// issued before the wait; vmcnt retires oldest-first, so vmcnt(N=loads of
// next tile) => current tile landed, next stays in flight ACROSS s_barrier.
#define WAITBAR_4 asm volatile("s_waitcnt vmcnt(4)\n\ts_barrier" ::: "memory")
#define WAITBAR_0 asm volatile("s_waitcnt vmcnt(0)\n\ts_barrier" ::: "memory")
#define BAR_ONLY  asm volatile("s_barrier" ::: "memory")

// ---------------- fused prep: cast x + transpose both weights ----------------
// grid sections: [0,4096) cast x; [4096,7168) transpose wqkv (96x32);
// [7168,8192) transpose wo (32x32).
__global__ __launch_bounds__(256) void prep(
    const float* __restrict__ x, u16* __restrict__ xb,
    const float* __restrict__ wqkv, u16* __restrict__ wqkvT,
    const float* __restrict__ wo, u16* __restrict__ woT) {
    __shared__ float tile[32][33];
    const int bid = blockIdx.x;
    const int t = threadIdx.x;
    if (bid < 4096) {
        int i = bid * 256 + t;
        f32x4 v = *(const f32x4*)(x + (size_t)i * 4);
        u16x4 o;
#pragma unroll
        for (int j = 0; j < 4; j++) o[j] = f2bf(v[j]);
        *(u16x4*)(xb + (size_t)i * 4) = o;
        return;
    }
    const float* src;
    u16* dst;
    int rows, cols, c0, r0;
    if (bid < 7168) {
        int b2 = bid - 4096;
        src = wqkv; dst = wqkvT; rows = 1024; cols = 3072;
        c0 = (b2 % 96) * 32; r0 = (b2 / 96) * 32;
    } else {
        int b3 = bid - 7168;
        src = wo; dst = woT; rows = 1024; cols = 1024;
        c0 = (b3 % 32) * 32; r0 = (b3 / 32) * 32;
    }
    int tx = t & 31, ty = t >> 5;   // (32,8)
#pragma unroll
    for (int i = 0; i < 4; i++)
        tile[ty + i * 8][tx] = src[(size_t)(r0 + ty + i * 8) * cols + c0 + tx];
    __syncthreads();
#pragma unroll
    for (int i = 0; i < 4; i++)
        dst[(size_t)(c0 + ty + i * 8) * rows + r0 + tx] = f2bf(tile[tx][ty + i * 8]);
}

// ---------------- GEMM1: qkv projection ----------------
// 128x128 tile, counted-vmcnt double-buffered K-loop (R6 pattern) + XCD
// swizzle: 768 blocks = 8 XCDs x 96; each XCD gets 4 contiguous m-rows x all
// 24 n-tiles -> A-panels fetched once per XCD instead of 8x.
// LDS: dbuf As/Bs = 32 KB, aliased with the 34 KB epilogue C-tile.
__global__ __launch_bounds__(256) void gemm_qkv(
    const u16* __restrict__ A, const u16* __restrict__ Bt,
    u16* __restrict__ qb, u16* __restrict__ kb, u16* __restrict__ vb) {
    __shared__ __align__(16) u16 smem[128 * 136];  // 34816 B
    // As(buf) = smem + buf*8192 ; Bs(buf) = smem + buf*8192 + 4096  (elements)
    const int t = threadIdx.x;
    const int wave = t >> 6;
    const int lane = t & 63;
    const int quad = lane >> 4;
    const int l16 = lane & 15;
    const int wr = wave >> 1;
    const int wc = wave & 1;
    const int bid = blockIdx.x;
    const int swz = (bid & 7) * 96 + (bid >> 3);   // 768 = 8*96, bijective
    const int n0 = (swz % 24) * 128;
    const int m0 = (swz / 24) * 128;

    f32x4 acc[4][4];
#pragma unroll
    for (int i = 0; i < 4; i++)
#pragma unroll
        for (int j = 0; j < 4; j++) acc[i][j] = {0.f, 0.f, 0.f, 0.f};

    // stage one 32-col K-step into buf: 4 loads/thread (2 A + 2 B)
#define QKV_STAGE(buf, col)                                                     \
    {                                                                           \
        _Pragma("unroll") for (int i = 0; i < 2; i++) {                         \
            int idx = i * 256 + t;                                              \
            int row = idx >> 2, kc = idx & 3;                                   \
            async_copy16(A + (size_t)(m0 + row) * 1024 + (col) + kc * 8,        \
                         &smem[(buf) * 8192 + idx * 8]);                        \
            async_copy16(Bt + (size_t)(n0 + row) * 1024 + (col) + kc * 8,       \
                         &smem[(buf) * 8192 + 4096 + idx * 8]);                 \
        }                                                                       \
    }

#define QKV_COMPUTE(buf)                                                        \
    {                                                                           \
        bf16x8 af[4], bfr[4];                                                   \
        _Pragma("unroll") for (int mt = 0; mt < 4; mt++)                        \
            af[mt] = *(const bf16x8*)&smem[(buf) * 8192 +                       \
                                           (wr * 64 + mt * 16 + l16) * 32 +    \
                                           quad * 8];                           \
        _Pragma("unroll") for (int nt = 0; nt < 4; nt++)                        \
            bfr[nt] = *(const bf16x8*)&smem[(buf) * 8192 + 4096 +               \
                                            (wc * 64 + nt * 16 + l16) * 32 +   \
                                            quad * 8];                          \
        _Pragma("unroll") for (int mt = 0; mt < 4; mt++)                        \
            _Pragma("unroll") for (int nt = 0; nt < 4; nt++)                    \
                acc[mt][nt] = __builtin_amdgcn_mfma_f32_16x16x32_bf16(          \
                    af[mt], bfr[nt], acc[mt][nt], 0, 0, 0);                     \
    }

    QKV_STAGE(0, 0);
    for (int ks = 0; ks < 31; ks++) {   // rolled: low VGPR (R5 lesson)
        const int cur = ks & 1;
        QKV_STAGE(cur ^ 1, (ks + 1) * 32);  // last vmem before the wait
        WAITBAR_4;                          // tile ks landed; ks+1 in flight
        QKV_COMPUTE(cur);
        BAR_ONLY;                           // buf cur reads done -> reusable
    }
    WAITBAR_0;                              // peeled last step (31) in buf 1
    QKV_COMPUTE(1);
    BAR_ONLY;                               // all fragment reads done before C overwrites smem

    // ---- epilogue: acc -> LDS [m][n] bf16 (stride 136) -> coalesced global
    const int tsel = n0 >> 10;  // 0=q 1=k 2=v (block-uniform)
    u16* dst = tsel == 0 ? qb : (tsel == 1 ? kb : vb);
    const float scl = tsel == 0 ? QSCALE : 1.0f;
#pragma unroll
    for (int mt = 0; mt < 4; mt++)
#pragma unroll
        for (int nt = 0; nt < 4; nt++) {
            int nn = wc * 64 + nt * 16 + l16;
#pragma unroll
            for (int r = 0; r < 4; r++) {
                int mm = wr * 64 + mt * 16 + quad * 4 + r;
                smem[mm * 136 + nn] = f2bf(acc[mt][nt][r] * scl);
            }
        }
    __syncthreads();
    const int col0 = (l16) * 8;       // 0..120, within one 64-d head (8-aligned)
    const int rowb = (t >> 4);        // 0..15
    const int h0 = (n0 & 1023) >> 6;  // first of the block's 2 heads
#pragma unroll
    for (int i = 0; i < 8; i++) {
        int row = i * 16 + rowb;      // 0..127
        u16x8 v = *(const u16x8*)&smem[row * 136 + col0];
        int h = h0 + (col0 >> 6), d = col0 & 63;
        int mm = m0 + row;
        int b = mm >> 11, s = mm & 2047;
        *(u16x8*)&dst[((size_t)((b * 16 + h) * 2048 + s)) * 64 + d] = v;
    }
}

// GEMM2 (fused with scale_v): out = (csum .* v) @ w_o, fp32 output.
// A-tile reg-staged from vb with on-the-fly colsum scaling. 64x128 tiles.
__global__ __launch_bounds__(256) void gemm_out(
    const u16* __restrict__ vb, const float* __restrict__ csum,
    const u16* __restrict__ Bt, float* __restrict__ out) {
    __shared__ __align__(16) u16 As[64 * 32];
    __shared__ __align__(16) u16 Bs[128 * 32];
    const int m0 = blockIdx.y * 64;
    const int n0 = blockIdx.x * 128;
    const int t = threadIdx.x;
    const int wave = t >> 6, lane = t & 63;
    const int quad = lane >> 4, l16 = lane & 15;
    const int wr = wave >> 1, wc = wave & 1;  // wave tile: 32 rows x 64 cols

    // fixed per-thread A coords: row m (b,s), col block (t&3)*8 within K-step
    const int arow = m0 + (t >> 2);
    const int ab = arow >> 11, as = arow & 2047;

    f32x4 acc[2][4];
#pragma unroll
    for (int i = 0; i < 2; i++)
#pragma unroll
        for (int j = 0; j < 4; j++) acc[i][j] = {0.f, 0.f, 0.f, 0.f};

    for (int kt = 0; kt < 1024; kt += 32) {
        {   // A: load vb, scale by csum[bh][s], write LDS
            int c = kt + (t & 3) * 8;          // col in [0,1024), 8-aligned
            int h = c >> 6, d0 = c & 63;
            int bh = ab * 16 + h;
            float cs = csum[bh * 2048 + as];
            u16x8 v = *(const u16x8*)&vb[((size_t)(bh * 2048 + as)) * 64 + d0];
            u16x8 o;
#pragma unroll
            for (int i = 0; i < 8; i++) o[i] = f2bf(bf2f(v[i]) * cs);
            *(u16x8*)&As[t * 8] = o;
        }
#pragma unroll
        for (int i = 0; i < 2; i++) {
            int idx = i * 256 + t;
            int row = idx >> 2, kc = idx & 3;
            async_copy16(Bt + (size_t)(n0 + row) * 1024 + kt + kc * 8, &Bs[idx * 8]);
        }
        __syncthreads();
        bf16x8 af[2], bfr[4];
#pragma unroll
        for (int mt = 0; mt < 2; mt++)
            af[mt] = *(const bf16x8*)&As[(wr * 32 + mt * 16 + l16) * 32 + quad * 8];
#pragma unroll
        for (int nt = 0; nt < 4; nt++)
            bfr[nt] = *(const bf16x8*)&Bs[(wc * 64 + nt * 16 + l16) * 32 + quad * 8];
#pragma unroll
        for (int mt = 0; mt < 2; mt++)
#pragma unroll
            for (int nt = 0; nt < 4; nt++)
                acc[mt][nt] = __builtin_amdgcn_mfma_f32_16x16x32_bf16(
                    af[mt], bfr[nt], acc[mt][nt], 0, 0, 0);
        __syncthreads();
    }
#pragma unroll
    for (int nt = 0; nt < 4; nt++) {
        int nn = n0 + wc * 64 + nt * 16 + l16;
#pragma unroll
        for (int mt = 0; mt < 2; mt++) {
#pragma unroll
            for (int r = 0; r < 4; r++) {
                int mm = m0 + wr * 32 + mt * 16 + quad * 4 + r;
                out[(size_t)mm * 1024 + nn] = acc[mt][nt][r];
            }
        }
    }
}

// ---------------- attention passes (R6 structure) ---------------
// No max subtraction: scores are O(+-5); exp(s)/sum(exp(s)) == softmax.
// Q pre-scaled by 0.125*log2e so weights are exp2(acc).
// 32x32x16 layouts: A/B [row=lane&31][k=f*16+(lane>>5)*8+j];
// C/D col=lane&31, row=(r&3)+8*(r>>2)+4*(lane>>5).
// Counted-vmcnt double-buffer pipeline (R6): STAGE(t+1) issued last, then
// fused "s_waitcnt vmcnt(4); s_barrier" -> tile t landed, t+1 in flight.

// Pass 1: block = 4 waves x 64 q-rows = 256 q-rows; k-chunk = 512 rows,
// staged as 4 tiles of 128 (XOR-swizzled, double-buffered). lp: 4 partials.
// Blocks 0..255 also zero csum (replaces the hipMemsetAsync dispatch; csum
// is only touched again by attn_pass2, after this kernel completes).
__global__ __launch_bounds__(256) void attn_pass1(
    const u16* __restrict__ qb, const u16* __restrict__ kb,
    float* __restrict__ lp, float* __restrict__ csum) {
    __shared__ __align__(16) u16 Ks[2][128 * 64];  // 2 x 16 KB, XOR-swizzled
    const int t = threadIdx.x;
    const int wave = t >> 6;
    const int lane = t & 63;
    const int l32 = lane & 31, half = lane >> 5;
    const int kchunk = blockIdx.x & 3;        // 512 k-rows each
    const int qblk = (blockIdx.x >> 2) & 7;   // 256 q-rows each
    const int bh = blockIdx.x >> 5;
    const int q0 = qblk * 256 + wave * 64;

    if (blockIdx.x < 256) csum[blockIdx.x * 256 + t] = 0.f;

    // persistent Q fragments, 2 q-sets: A[m=l32][k=f*16+half*8+j]
    bf16x8 a[2][4];
#pragma unroll
    for (int qs = 0; qs < 2; qs++) {
        const u16* Qr = qb + (size_t)(bh * 2048 + q0 + qs * 32 + l32) * 64 + half * 8;
#pragma unroll
        for (int f = 0; f < 4; f++) a[qs][f] = *(const bf16x8*)&Qr[f * 16];
    }

    const u16* Kbase = kb + (size_t)(bh * 2048 + kchunk * 512) * 64;

    float lsum[2][16];
#pragma unroll
    for (int qs = 0; qs < 2; qs++)
#pragma unroll
        for (int r = 0; r < 16; r++) lsum[qs][r] = 0.f;

    f32x16 ZZ;
#pragma unroll
    for (int r = 0; r < 16; r++) ZZ[r] = 0.f;

    // STAGE one 128-row tile: LDS[row][blk] = G[row][blk ^ (row&7)]
#define STAGE_K(buf, kt)                                                        \
    {                                                                           \
        _Pragma("unroll") for (int i = 0; i < 4; i++) {                         \
            int idx = i * 256 + t;                                              \
            int row = idx >> 3;                                                 \
            int blk = (idx & 7) ^ (row & 7);                                    \
            async_copy16(Kbase + (size_t)((kt) * 128 + row) * 64 + blk * 8,     \
                         &Ks[buf][idx * 8]);                                    \
        }                                                                       \
    }

#define COMPUTE_K(cur)                                                          \
    {                                                                           \
        _Pragma("unroll") for (int sub = 0; sub < 4; sub++) {                   \
            const int row = sub * 32 + l32;                                     \
            const int r7 = row & 7;                                             \
            bf16x8 bfr[4];                                                      \
            _Pragma("unroll") for (int f = 0; f < 4; f++)                       \
                bfr[f] = *(const bf16x8*)&Ks[cur][row * 64 +                    \
                                                 (((f * 2 + half)) ^ r7) * 8];  \
            __builtin_amdgcn_s_setprio(1);                                      \
            _Pragma("unroll") for (int qs = 0; qs < 2; qs++) {                  \
                f32x16 acc = __builtin_amdgcn_mfma_f32_32x32x16_bf16(           \
                    a[qs][0], bfr[0], ZZ, 0, 0, 0);                             \
                _Pragma("unroll") for (int f = 1; f < 4; f++)                   \
                    acc = __builtin_amdgcn_mfma_f32_32x32x16_bf16(              \
                        a[qs][f], bfr[f], acc, 0, 0, 0);                        \
                __builtin_amdgcn_s_setprio(0);                                  \
                _Pragma("unroll") for (int r = 0; r < 16; r++)                  \
                    lsum[qs][r] += __builtin_amdgcn_exp2f(acc[r]);              \
                __builtin_amdgcn_s_setprio(1);                                  \
            }                                                                   \
            __builtin_amdgcn_s_setprio(0);                                     \
        }                                                                       \
    }

    STAGE_K(0, 0);
    for (int kt = 0; kt < 3; kt++) {   // rolled: small code, low VGPR
        const int cur = kt & 1;
        STAGE_K(cur ^ 1, kt + 1);      // last vmem issued before the wait
        WAITBAR_4;                     // tile kt landed; kt+1 in flight
        COMPUTE_K(cur);
        BAR_ONLY;                      // Ks[cur] reads done -> reusable
    }
    WAITBAR_0;                         // peeled last tile (3) in buf 1
    COMPUTE_K(1);

    // reduce each row across the 32 k-columns (lanes within each half)
#pragma unroll
    for (int qs = 0; qs < 2; qs++) {
#pragma unroll
        for (int r = 0; r < 16; r++) {
            float v = lsum[qs][r];
            v += __shfl_xor(v, 1);
            v += __shfl_xor(v, 2);
            v += __shfl_xor(v, 4);
            v += __shfl_xor(v, 8);
            v += __shfl_xor(v, 16);
            lsum[qs][r] = v;
        }
    }
    if (l32 == 0) {
#pragma unroll
        for (int qs = 0; qs < 2; qs++) {
            float* dst = lp + kchunk * 65536 + bh * 2048 + q0 + qs * 32 + half * 4;
#pragma unroll
            for (int r = 0; r < 16; r++)
                dst[(r & 3) + 8 * (r >> 2)] = lsum[qs][r];
        }
    }
}

// Pass 2: block = 4 waves x 64 k-cols = 256 k-cols; q-chunk = 512 rows,
// staged as 4 tiles of 128; li = 1/(sum of 4 lp partials) in LDS.
// Colsum accumulated into csum via atomicAdd (csum zeroed by pass1).
__global__ __launch_bounds__(256) void attn_pass2(
    const u16* __restrict__ qb, const u16* __restrict__ kb,
    const float* __restrict__ lp, float* __restrict__ csum) {
    __shared__ __align__(16) u16 Qs[2][128 * 64];  // 2 x 16 KB, XOR-swizzled
    __shared__ __align__(16) float li_lds[512];
    const int t = threadIdx.x;
    const int wave = t >> 6;
    const int lane = t & 63;
    const int l32 = lane & 31, half = lane >> 5;
    const int qchunk = blockIdx.x & 3;        // 512 q-rows each
    const int kblk = (blockIdx.x >> 2) & 7;   // 256 k-cols each
    const int bh = blockIdx.x >> 5;
    const int k0 = kblk * 256 + wave * 64;

    // li table for this block's 512 q-rows
    {
        const int base = bh * 2048 + qchunk * 512;
#pragma unroll
        for (int i = 0; i < 2; i++) {
            int q = i * 256 + t;
            float s = lp[base + q] + lp[65536 + base + q] + lp[131072 + base + q] +
                      lp[196608 + base + q];
            li_lds[q] = 1.0f / s;
        }
    }

    // persistent K fragments, 2 k-sets: B[n=l32][k=f*16+half*8+j]
    bf16x8 b[2][4];
#pragma unroll
    for (int ks = 0; ks < 2; ks++) {
        const u16* Kr = kb + (size_t)(bh * 2048 + k0 + ks * 32 + l32) * 64 + half * 8;
#pragma unroll
        for (int f = 0; f < 4; f++) b[ks][f] = *(const bf16x8*)&Kr[f * 16];
    }

    const u16* Qbase = qb + (size_t)(bh * 2048 + qchunk * 512) * 64;

    f32x16 ZZ;
#pragma unroll
    for (int r = 0; r < 16; r++) ZZ[r] = 0.f;

#define STAGE_Q(buf, qt)                                                        \
    {                                                                           \
        _Pragma("unroll") for (int i = 0; i < 4; i++) {                         \
            int idx = i * 256 + t;                                              \
            int row = idx >> 3;                                                 \
            int blk = (idx & 7) ^ (row & 7);                                    \
            async_copy16(Qbase + (size_t)((qt) * 128 + row) * 64 + blk * 8,     \
                         &Qs[buf][idx * 8]);                                    \
        }                                                                       \
    }

#define COMPUTE_Q(cur, qt)                                                      \
    {                                                                           \
        _Pragma("unroll") for (int sub = 0; sub < 4; sub++) {                   \
            const int row = sub * 32 + l32;                                     \
            const int r7 = row & 7;                                             \
            bf16x8 af[4];                                                       \
            _Pragma("unroll") for (int f = 0; f < 4; f++)                       \
                af[f] = *(const bf16x8*)&Qs[cur][row * 64 +                     \
                                                 (((f * 2 + half)) ^ r7) * 8];  \
            const float* lr = &li_lds[(qt) * 128 + sub * 32 + half * 4];        \
            f32x4 li0 = *(const f32x4*)&lr[0];                                  \
            f32x4 li1 = *(const f32x4*)&lr[8];                                  \
            f32x4 li2 = *(const f32x4*)&lr[16];                                 \
            f32x4 li3 = *(const f32x4*)&lr[24];                                 \
            __builtin_amdgcn_s_setprio(1);                                      \
            _Pragma("unroll") for (int ks = 0; ks < 2; ks++) {                  \
                f32x16 acc = __builtin_amdgcn_mfma_f32_32x32x16_bf16(           \
                    af[0], b[ks][0], ZZ, 0, 0, 0);                              \
                _Pragma("unroll") for (int f = 1; f < 4; f++)                   \
                    acc = __builtin_amdgcn_mfma_f32_32x32x16_bf16(              \
                        af[f], b[ks][f], acc, 0, 0, 0);                         \
                __builtin_amdgcn_s_setprio(0);                                  \
                float c = cs[ks];                                               \
                _Pragma("unroll") for (int r = 0; r < 4; r++)                   \
                    c += __builtin_amdgcn_exp2f(acc[r]) * li0[r];               \
                _Pragma("unroll") for (int r = 0; r < 4; r++)                   \
                    c += __builtin_amdgcn_exp2f(acc[4 + r]) * li1[r];           \
                _Pragma("unroll") for (int r = 0; r < 4; r++)                   \
                    c += __builtin_amdgcn_exp2f(acc[8 + r]) * li2[r];           \
                _Pragma("unroll") for (int r = 0; r < 4; r++)                   \
                    c += __builtin_amdgcn_exp2f(acc[12 + r]) * li3[r];          \
                cs[ks] = c;                                                     \
                __builtin_amdgcn_s_setprio(1);                                  \
            }                                                                   \
            __builtin_amdgcn_s_setprio(0);                                     \
        }                                                                       \
    }

    float cs[2] = {0.f, 0.f};
    __syncthreads();      // li_lds visible (drains only lp loads; no STAGE yet)
    STAGE_Q(0, 0);

    for (int qt = 0; qt < 3; qt++) {   // rolled
        const int cur = qt & 1;
        STAGE_Q(cur ^ 1, qt + 1);      // last vmem issued before the wait
        WAITBAR_4;                     // tile qt landed; qt+1 in flight
        COMPUTE_Q(cur, qt);
        BAR_ONLY;                      // Qs[cur] reads done -> reusable
    }
    WAITBAR_0;                         // peeled last tile (3) in buf 1
    COMPUTE_Q(1, 3);

#pragma unroll
    for (int ks = 0; ks < 2; ks++) {
        float v = cs[ks] + __shfl_xor(cs[ks], 32);
        if (lane < 32)
            atomicAdd(&csum[bh * 2048 + k0 + ks * 32 + lane], v);
    }
}

// ---------------- launch ----------------

extern "C" void kernel_launch(void* const* d_in, const int* in_sizes, int n_in,
                              void* d_out, int out_size, void* d_ws, size_t ws_size,
                              hipStream_t stream) {
    const float* x    = (const float*)d_in[0];   // [2,2048,1024]
    const float* wqkv = (const float*)d_in[1];   // [1024,3072]
    const float* wo   = (const float*)d_in[2];   // [1024,1024]
    float* out = (float*)d_out;                  // [2,2048,1024] fp32
    char* ws = (char*)d_ws;

    u16* xb      = (u16*)(ws);                   // [4096][1024] bf16 (dead after gemm_qkv)
    u16* wqkvT   = (u16*)(ws + 8388608);         // [3072][1024] bf16
    u16* woT     = (u16*)(ws + 14680064);        // [1024][1024] bf16
    u16* qb      = (u16*)(ws + 16777216);        // [32][2048][64] bf16
    u16* kb      = (u16*)(ws + 25165824);
    u16* vb      = (u16*)(ws + 33554432);
    // lp aliases xb (dead after gemm_qkv); csum lives in the free high region
    float* lp    = (float*)(ws);                 // [4][32][2048]
    float* csum  = (float*)(ws + 42467328);      // [32][2048] summed colsum

    prep<<<8192, 256, 0, stream>>>(x, xb, wqkv, wqkvT, wo, woT);
    gemm_qkv<<<768, 256, 0, stream>>>(xb, wqkvT, qb, kb, vb);
    attn_pass1<<<1024, 256, 0, stream>>>(qb, kb, lp, csum);
    attn_pass2<<<1024, 256, 0, stream>>>(qb, kb, lp, csum);
    gemm_out<<<dim3(8, 64), 256, 0, stream>>>(vb, csum, woT, out);
}

// Round 10
// 199.607 us; speedup vs baseline: 1.0145x; 1.0005x over previous
//
#include <hip/hip_runtime.h>
#include <stdint.h>

// Problem constants: B=2, S=2048, HIDDEN=1024, NH=16, D=64
// M = B*S = 4096, N1 = 3072, K = 1024, N2 = 1024, BH = 32

#define DEV static __device__ __forceinline__

typedef unsigned short u16;
typedef __attribute__((ext_vector_type(4))) float f32x4;
typedef __attribute__((ext_vector_type(16))) float f32x16;
typedef __bf16 bf16x8 __attribute__((ext_vector_type(8)));
typedef __attribute__((ext_vector_type(8))) unsigned short u16x8;
typedef __attribute__((ext_vector_type(4))) unsigned short u16x4;

// 0.125 * log2(e): folded into Q so softmax weights are exp2(acc)
#define QSCALE 0.18033688011112042f

DEV u16 f2bf(float f) {
    unsigned u = __builtin_bit_cast(unsigned, f);
    u += 0x7fffu + ((u >> 16) & 1u);
    return (u16)(u >> 16);
}
DEV float bf2f(u16 h) {
    unsigned u = ((unsigned)h) << 16;
    return __builtin_bit_cast(float, u);
}

// async global->LDS, 16B per lane. LDS dest must be wave-uniform base + lane*16.
DEV void async_copy16(const void* g, void* l) {
    __builtin_amdgcn_global_load_lds(
        (__attribute__((address_space(1))) void*)(g),
        (__attribute__((address_space(3))) void*)(l), 16, 0, 0);
}

// counted-vmcnt barrier pairs (validated R6, SINGLE-deep, gload_lds-only
// vmcnt stream): STAGE(next) is the last vmem issued before the wait; vmcnt
// retires oldest-first, so vmcnt(4) => current tile landed, next tile's 4
// loads stay in flight ACROSS s_barrier. R9 lesson: do NOT mix VGPR-returning
// loads into a counted gload_lds stream, and keep depth=1 (2-deep + mixed
// stream failed correctness).
#define WAITBAR_4 asm volatile("s_waitcnt vmcnt(4)\n\ts_barrier" ::: "memory")
#define WAITBAR_0 asm volatile("s_waitcnt vmcnt(0)\n\ts_barrier" ::: "memory")
#define BAR_ONLY  asm volatile("s_barrier" ::: "memory")

// ---------------- fused prep: cast x + transpose both weights ----------------
// grid sections: [0,4096) cast x; [4096,7168) transpose wqkv (96x32);
// [7168,8192) transpose wo (32x32).
__global__ __launch_bounds__(256) void prep(
    const float* __restrict__ x, u16* __restrict__ xb,
    const float* __restrict__ wqkv, u16* __restrict__ wqkvT,
    const float* __restrict__ wo, u16* __restrict__ woT) {
    __shared__ float tile[32][33];
    const int bid = blockIdx.x;
    const int t = threadIdx.x;
    if (bid < 4096) {
        int i = bid * 256 + t;
        f32x4 v = *(const f32x4*)(x + (size_t)i * 4);
        u16x4 o;
#pragma unroll
        for (int j = 0; j < 4; j++) o[j] = f2bf(v[j]);
        *(u16x4*)(xb + (size_t)i * 4) = o;
        return;
    }
    const float* src;
    u16* dst;
    int rows, cols, c0, r0;
    if (bid < 7168) {
        int b2 = bid - 4096;
        src = wqkv; dst = wqkvT; rows = 1024; cols = 3072;
        c0 = (b2 % 96) * 32; r0 = (b2 / 96) * 32;
    } else {
        int b3 = bid - 7168;
        src = wo; dst = woT; rows = 1024; cols = 1024;
        c0 = (b3 % 32) * 32; r0 = (b3 / 32) * 32;
    }
    int tx = t & 31, ty = t >> 5;   // (32,8)
#pragma unroll
    for (int i = 0; i < 4; i++)
        tile[ty + i * 8][tx] = src[(size_t)(r0 + ty + i * 8) * cols + c0 + tx];
    __syncthreads();
#pragma unroll
    for (int i = 0; i < 4; i++)
        dst[(size_t)(c0 + ty + i * 8) * rows + r0 + tx] = f2bf(tile[tx][ty + i * 8]);
}

// ---------------- GEMM1: qkv projection ----------------
// 128x128 tile; 2-buffer counted-vmcnt pipeline (R6-validated depth) + LDS
// XOR-swizzle via pre-swizzled global source: LDS[row][kc] = G[row][kc^(row&3)],
// fragment read block quad^(row&3) -> G[row][quad]. (R8 PMC: 3.24M
// bank-conflict cycles from 8-way fragment reads at 64B row stride.)
// XCD swizzle: 768 = 8 XCDs x 96 (4 m-rows x 24 n-tiles each).
__global__ __launch_bounds__(256) void gemm_qkv(
    const u16* __restrict__ A, const u16* __restrict__ Bt,
    u16* __restrict__ qb, u16* __restrict__ kb, u16* __restrict__ vb) {
    __shared__ __align__(16) u16 smem[128 * 136];  // 34816 B
    // As(buf) = smem + buf*8192 ; Bs(buf) = smem + buf*8192 + 4096  (elements)
    const int t = threadIdx.x;
    const int wave = t >> 6;
    const int lane = t & 63;
    const int quad = lane >> 4;
    const int l16 = lane & 15;
    const int wr = wave >> 1;
    const int wc = wave & 1;
    const int bid = blockIdx.x;
    const int swz = (bid & 7) * 96 + (bid >> 3);   // 768 = 8*96, bijective
    const int n0 = (swz % 24) * 128;
    const int m0 = (swz / 24) * 128;

    f32x4 acc[4][4];
#pragma unroll
    for (int i = 0; i < 4; i++)
#pragma unroll
        for (int j = 0; j < 4; j++) acc[i][j] = {0.f, 0.f, 0.f, 0.f};

    // stage one 32-col K-step into buf: LDS[row][kc] = G[row][kc ^ (row&3)]
#define QKV_STAGE(buf, col)                                                     \
    {                                                                           \
        _Pragma("unroll") for (int i = 0; i < 2; i++) {                         \
            int idx = i * 256 + t;                                              \
            int row = idx >> 2, kc = idx & 3;                                   \
            int sb = kc ^ (row & 3);                                            \
            async_copy16(A + (size_t)(m0 + row) * 1024 + (col) + sb * 8,        \
                         &smem[(buf) * 8192 + idx * 8]);                        \
            async_copy16(Bt + (size_t)(n0 + row) * 1024 + (col) + sb * 8,       \
                         &smem[(buf) * 8192 + 4096 + idx * 8]);                 \
        }                                                                       \
    }

#define QKV_COMPUTE(buf)                                                        \
    {                                                                           \
        bf16x8 af[4], bfr[4];                                                   \
        _Pragma("unroll") for (int mt = 0; mt < 4; mt++) {                      \
            int row = wr * 64 + mt * 16 + l16;                                  \
            af[mt] = *(const bf16x8*)&smem[(buf) * 8192 + row * 32 +            \
                                           (quad ^ (row & 3)) * 8];             \
        }                                                                       \
        _Pragma("unroll") for (int nt = 0; nt < 4; nt++) {                      \
            int row = wc * 64 + nt * 16 + l16;                                  \
            bfr[nt] = *(const bf16x8*)&smem[(buf) * 8192 + 4096 + row * 32 +    \
                                            (quad ^ (row & 3)) * 8];            \
        }                                                                       \
        _Pragma("unroll") for (int mt = 0; mt < 4; mt++)                        \
            _Pragma("unroll") for (int nt = 0; nt < 4; nt++)                    \
                acc[mt][nt] = __builtin_amdgcn_mfma_f32_16x16x32_bf16(          \
                    af[mt], bfr[nt], acc[mt][nt], 0, 0, 0);                     \
    }

    QKV_STAGE(0, 0);
    for (int ks = 0; ks < 31; ks++) {   // rolled: low VGPR (R5 lesson)
        const int cur = ks & 1;
        QKV_STAGE(cur ^ 1, (ks + 1) * 32);  // last vmem before the wait
        WAITBAR_4;                          // tile ks landed; ks+1 in flight
        QKV_COMPUTE(cur);
        BAR_ONLY;                           // buf cur reads done -> reusable
    }
    WAITBAR_0;                              // peeled last step (31) in buf 1
    QKV_COMPUTE(1);
    BAR_ONLY;                               // fragment reads done before C aliases smem

    // ---- epilogue: acc -> LDS [m][n] bf16 (stride 136) -> coalesced global
    const int tsel = n0 >> 10;  // 0=q 1=k 2=v (block-uniform)
    u16* dst = tsel == 0 ? qb : (tsel == 1 ? kb : vb);
    const float scl = tsel == 0 ? QSCALE : 1.0f;
#pragma unroll
    for (int mt = 0; mt < 4; mt++)
#pragma unroll
        for (int nt = 0; nt < 4; nt++) {
            int nn = wc * 64 + nt * 16 + l16;
#pragma unroll
            for (int r = 0; r < 4; r++) {
                int mm = wr * 64 + mt * 16 + quad * 4 + r;
                smem[mm * 136 + nn] = f2bf(acc[mt][nt][r] * scl);
            }
        }
    __syncthreads();
    const int col0 = (l16) * 8;       // 0..120, within one 64-d head (8-aligned)
    const int rowb = (t >> 4);        // 0..15
    const int h0 = (n0 & 1023) >> 6;  // first of the block's 2 heads
#pragma unroll
    for (int i = 0; i < 8; i++) {
        int row = i * 16 + rowb;      // 0..127
        u16x8 v = *(const u16x8*)&smem[row * 136 + col0];
        int h = h0 + (col0 >> 6), d = col0 & 63;
        int mm = m0 + row;
        int b = mm >> 11, s = mm & 2047;
        *(u16x8*)&dst[((size_t)((b * 16 + h) * 2048 + s)) * 64 + d] = v;
    }
}

// GEMM2 (fused with scale_v): out = (csum .* v) @ w_o, fp32 output.
// R8-proven version (serial A reg-stage + __syncthreads): R9's T14/mixed
// counted-vmcnt variant failed correctness. 64x128 tiles -> 512 blocks.
__global__ __launch_bounds__(256) void gemm_out(
    const u16* __restrict__ vb, const float* __restrict__ csum,
    const u16* __restrict__ Bt, float* __restrict__ out) {
    __shared__ __align__(16) u16 As[64 * 32];
    __shared__ __align__(16) u16 Bs[128 * 32];
    const int m0 = blockIdx.y * 64;
    const int n0 = blockIdx.x * 128;
    const int t = threadIdx.x;
    const int wave = t >> 6, lane = t & 63;
    const int quad = lane >> 4, l16 = lane & 15;
    const int wr = wave >> 1, wc = wave & 1;  // wave tile: 32 rows x 64 cols

    // fixed per-thread A coords: row m (b,s), col block (t&3)*8 within K-step
    const int arow = m0 + (t >> 2);
    const int ab = arow >> 11, as = arow & 2047;

    f32x4 acc[2][4];
#pragma unroll
    for (int i = 0; i < 2; i++)
#pragma unroll
        for (int j = 0; j < 4; j++) acc[i][j] = {0.f, 0.f, 0.f, 0.f};

    for (int kt = 0; kt < 1024; kt += 32) {
        {   // A: load vb, scale by csum[bh][s], write LDS
            int c = kt + (t & 3) * 8;          // col in [0,1024), 8-aligned
            int h = c >> 6, d0 = c & 63;
            int bh = ab * 16 + h;
            float cs = csum[bh * 2048 + as];
            u16x8 v = *(const u16x8*)&vb[((size_t)(bh * 2048 + as)) * 64 + d0];
            u16x8 o;
#pragma unroll
            for (int i = 0; i < 8; i++) o[i] = f2bf(bf2f(v[i]) * cs);
            *(u16x8*)&As[t * 8] = o;
        }
#pragma unroll
        for (int i = 0; i < 2; i++) {
            int idx = i * 256 + t;
            int row = idx >> 2, kc = idx & 3;
            async_copy16(Bt + (size_t)(n0 + row) * 1024 + kt + kc * 8, &Bs[idx * 8]);
        }
        __syncthreads();
        bf16x8 af[2], bfr[4];
#pragma unroll
        for (int mt = 0; mt < 2; mt++)
            af[mt] = *(const bf16x8*)&As[(wr * 32 + mt * 16 + l16) * 32 + quad * 8];
#pragma unroll
        for (int nt = 0; nt < 4; nt++)
            bfr[nt] = *(const bf16x8*)&Bs[(wc * 64 + nt * 16 + l16) * 32 + quad * 8];
#pragma unroll
        for (int mt = 0; mt < 2; mt++)
#pragma unroll
            for (int nt = 0; nt < 4; nt++)
                acc[mt][nt] = __builtin_amdgcn_mfma_f32_16x16x32_bf16(
                    af[mt], bfr[nt], acc[mt][nt], 0, 0, 0);
        __syncthreads();
    }
#pragma unroll
    for (int nt = 0; nt < 4; nt++) {
        int nn = n0 + wc * 64 + nt * 16 + l16;
#pragma unroll
        for (int mt = 0; mt < 2; mt++) {
#pragma unroll
            for (int r = 0; r < 4; r++) {
                int mm = m0 + wr * 32 + mt * 16 + quad * 4 + r;
                out[(size_t)mm * 1024 + nn] = acc[mt][nt][r];
            }
        }
    }
}

// ---------------- attention passes (R6 structure, unchanged) ---------------
// No max subtraction: scores are O(+-5); exp(s)/sum(exp(s)) == softmax.
// Q pre-scaled by 0.125*log2e so weights are exp2(acc).
// 32x32x16 layouts: A/B [row=lane&31][k=f*16+(lane>>5)*8+j];
// C/D col=lane&31, row=(r&3)+8*(r>>2)+4*(lane>>5).

// Pass 1: block = 4 waves x 64 q-rows = 256 q-rows; k-chunk = 512 rows,
// staged as 4 tiles of 128 (XOR-swizzled, double-buffered). lp: 4 partials.
// Blocks 0..255 also zero csum (pass2 touches csum only after pass1 ends).
__global__ __launch_bounds__(256) void attn_pass1(
    const u16* __restrict__ qb, const u16* __restrict__ kb,
    float* __restrict__ lp, float* __restrict__ csum) {
    __shared__ __align__(16) u16 Ks[2][128 * 64];  // 2 x 16 KB, XOR-swizzled
    const int t = threadIdx.x;
    const int wave = t >> 6;
    const int lane = t & 63;
    const int l32 = lane & 31, half = lane >> 5;
    const int kchunk = blockIdx.x & 3;        // 512 k-rows each
    const int qblk = (blockIdx.x >> 2) & 7;   // 256 q-rows each
    const int bh = blockIdx.x >> 5;
    const int q0 = qblk * 256 + wave * 64;

    if (blockIdx.x < 256) csum[blockIdx.x * 256 + t] = 0.f;

    // persistent Q fragments, 2 q-sets: A[m=l32][k=f*16+half*8+j]
    bf16x8 a[2][4];
#pragma unroll
    for (int qs = 0; qs < 2; qs++) {
        const u16* Qr = qb + (size_t)(bh * 2048 + q0 + qs * 32 + l32) * 64 + half * 8;
#pragma unroll
        for (int f = 0; f < 4; f++) a[qs][f] = *(const bf16x8*)&Qr[f * 16];
    }

    const u16* Kbase = kb + (size_t)(bh * 2048 + kchunk * 512) * 64;

    float lsum[2][16];
#pragma unroll
    for (int qs = 0; qs < 2; qs++)
#pragma unroll
        for (int r = 0; r < 16; r++) lsum[qs][r] = 0.f;

    f32x16 ZZ;
#pragma unroll
    for (int r = 0; r < 16; r++) ZZ[r] = 0.f;

    // STAGE one 128-row tile: LDS[row][blk] = G[row][blk ^ (row&7)]
#define STAGE_K(buf, kt)                                                        \
    {                                                                           \
        _Pragma("unroll") for (int i = 0; i < 4; i++) {                         \
            int idx = i * 256 + t;                                              \
            int row = idx >> 3;                                                 \
            int blk = (idx & 7) ^ (row & 7);                                    \
            async_copy16(Kbase + (size_t)((kt) * 128 + row) * 64 + blk * 8,     \
                         &Ks[buf][idx * 8]);                                    \
        }                                                                       \
    }

#define COMPUTE_K(cur)                                                          \
    {                                                                           \
        _Pragma("unroll") for (int sub = 0; sub < 4; sub++) {                   \
            const int row = sub * 32 + l32;                                     \
            const int r7 = row & 7;                                             \
            bf16x8 bfr[4];                                                      \
            _Pragma("unroll") for (int f = 0; f < 4; f++)                       \
                bfr[f] = *(const bf16x8*)&Ks[cur][row * 64 +                    \
                                                 (((f * 2 + half)) ^ r7) * 8];  \
            __builtin_amdgcn_s_setprio(1);                                      \
            _Pragma("unroll") for (int qs = 0; qs < 2; qs++) {                  \
                f32x16 acc = __builtin_amdgcn_mfma_f32_32x32x16_bf16(           \
                    a[qs][0], bfr[0], ZZ, 0, 0, 0);                             \
                _Pragma("unroll") for (int f = 1; f < 4; f++)                   \
                    acc = __builtin_amdgcn_mfma_f32_32x32x16_bf16(              \
                        a[qs][f], bfr[f], acc, 0, 0, 0);                        \
                __builtin_amdgcn_s_setprio(0);                                  \
                _Pragma("unroll") for (int r = 0; r < 16; r++)                  \
                    lsum[qs][r] += __builtin_amdgcn_exp2f(acc[r]);              \
                __builtin_amdgcn_s_setprio(1);                                  \
            }                                                                   \
            __builtin_amdgcn_s_setprio(0);                                     \
        }                                                                       \
    }

    STAGE_K(0, 0);
    for (int kt = 0; kt < 3; kt++) {   // rolled: small code, low VGPR
        const int cur = kt & 1;
        STAGE_K(cur ^ 1, kt + 1);      // last vmem issued before the wait
        WAITBAR_4;                     // tile kt landed; kt+1 in flight
        COMPUTE_K(cur);
        BAR_ONLY;                      // Ks[cur] reads done -> reusable
    }
    WAITBAR_0;                         // peeled last tile (3) in buf 1
    COMPUTE_K(1);

    // reduce each row across the 32 k-columns (lanes within each half)
#pragma unroll
    for (int qs = 0; qs < 2; qs++) {
#pragma unroll
        for (int r = 0; r < 16; r++) {
            float v = lsum[qs][r];
            v += __shfl_xor(v, 1);
            v += __shfl_xor(v, 2);
            v += __shfl_xor(v, 4);
            v += __shfl_xor(v, 8);
            v += __shfl_xor(v, 16);
            lsum[qs][r] = v;
        }
    }
    if (l32 == 0) {
#pragma unroll
        for (int qs = 0; qs < 2; qs++) {
            float* dst = lp + kchunk * 65536 + bh * 2048 + q0 + qs * 32 + half * 4;
#pragma unroll
            for (int r = 0; r < 16; r++)
                dst[(r & 3) + 8 * (r >> 2)] = lsum[qs][r];
        }
    }
}

// Pass 2: block = 4 waves x 64 k-cols = 256 k-cols; q-chunk = 512 rows,
// staged as 4 tiles of 128; li = 1/(sum of 4 lp partials) in LDS.
// Colsum accumulated into csum via atomicAdd (csum zeroed by pass1).
__global__ __launch_bounds__(256) void attn_pass2(
    const u16* __restrict__ qb, const u16* __restrict__ kb,
    const float* __restrict__ lp, float* __restrict__ csum) {
    __shared__ __align__(16) u16 Qs[2][128 * 64];  // 2 x 16 KB, XOR-swizzled
    __shared__ __align__(16) float li_lds[512];
    const int t = threadIdx.x;
    const int wave = t >> 6;
    const int lane = t & 63;
    const int l32 = lane & 31, half = lane >> 5;
    const int qchunk = blockIdx.x & 3;        // 512 q-rows each
    const int kblk = (blockIdx.x >> 2) & 7;   // 256 k-cols each
    const int bh = blockIdx.x >> 5;
    const int k0 = kblk * 256 + wave * 64;

    // li table for this block's 512 q-rows
    {
        const int base = bh * 2048 + qchunk * 512;
#pragma unroll
        for (int i = 0; i < 2; i++) {
            int q = i * 256 + t;
            float s = lp[base + q] + lp[65536 + base + q] + lp[131072 + base + q] +
                      lp[196608 + base + q];
            li_lds[q] = 1.0f / s;
        }
    }

    // persistent K fragments, 2 k-sets: B[n=l32][k=f*16+half*8+j]
    bf16x8 b[2][4];
#pragma unroll
    for (int ks = 0; ks < 2; ks++) {
        const u16* Kr = kb + (size_t)(bh * 2048 + k0 + ks * 32 + l32) * 64 + half * 8;
#pragma unroll
        for (int f = 0; f < 4; f++) b[ks][f] = *(const bf16x8*)&Kr[f * 16];
    }

    const u16* Qbase = qb + (size_t)(bh * 2048 + qchunk * 512) * 64;

    f32x16 ZZ;
#pragma unroll
    for (int r = 0; r < 16; r++) ZZ[r] = 0.f;

#define STAGE_Q(buf, qt)                                                        \
    {                                                                           \
        _Pragma("unroll") for (int i = 0; i < 4; i++) {                         \
            int idx = i * 256 + t;                                              \
            int row = idx >> 3;                                                 \
            int blk = (idx & 7) ^ (row & 7);                                    \
            async_copy16(Qbase + (size_t)((qt) * 128 + row) * 64 + blk * 8,     \
                         &Qs[buf][idx * 8]);                                    \
        }                                                                       \
    }

#define COMPUTE_Q(cur, qt)                                                      \
    {                                                                           \
        _Pragma("unroll") for (int sub = 0; sub < 4; sub++) {                   \
            const int row = sub * 32 + l32;                                     \
            const int r7 = row & 7;                                             \
            bf16x8 af[4];                                                       \
            _Pragma("unroll") for (int f = 0; f < 4; f++)                       \
                af[f] = *(const bf16x8*)&Qs[cur][row * 64 +                     \
                                                 (((f * 2 + half)) ^ r7) * 8];  \
            const float* lr = &li_lds[(qt) * 128 + sub * 32 + half * 4];        \
            f32x4 li0 = *(const f32x4*)&lr[0];                                  \
            f32x4 li1 = *(const f32x4*)&lr[8];                                  \
            f32x4 li2 = *(const f32x4*)&lr[16];                                 \
            f32x4 li3 = *(const f32x4*)&lr[24];                                 \
            __builtin_amdgcn_s_setprio(1);                                      \
            _Pragma("unroll") for (int ks = 0; ks < 2; ks++) {                  \
                f32x16 acc = __builtin_amdgcn_mfma_f32_32x32x16_bf16(           \
                    af[0], b[ks][0], ZZ, 0, 0, 0);                              \
                _Pragma("unroll") for (int f = 1; f < 4; f++)                   \
                    acc = __builtin_amdgcn_mfma_f32_32x32x16_bf16(              \
                        af[f], b[ks][f], acc, 0, 0, 0);                         \
                __builtin_amdgcn_s_setprio(0);                                  \
                float c = cs[ks];                                               \
                _Pragma("unroll") for (int r = 0; r < 4; r++)                   \
                    c += __builtin_amdgcn_exp2f(acc[r]) * li0[r];               \
                _Pragma("unroll") for (int r = 0; r < 4; r++)                   \
                    c += __builtin_amdgcn_exp2f(acc[4 + r]) * li1[r];           \
                _Pragma("unroll") for (int r = 0; r < 4; r++)                   \
                    c += __builtin_amdgcn_exp2f(acc[8 + r]) * li2[r];           \
                _Pragma("unroll") for (int r = 0; r < 4; r++)                   \
                    c += __builtin_amdgcn_exp2f(acc[12 + r]) * li3[r];          \
                cs[ks] = c;                                                     \
                __builtin_amdgcn_s_setprio(1);                                  \
            }                                                                   \
            __builtin_amdgcn_s_setprio(0);                                     \
        }                                                                       \
    }

    float cs[2] = {0.f, 0.f};
    __syncthreads();      // li_lds visible (drains only lp loads; no STAGE yet)
    STAGE_Q(0, 0);

    for (int qt = 0; qt < 3; qt++) {   // rolled
        const int cur = qt & 1;
        STAGE_Q(cur ^ 1, qt + 1);      // last vmem issued before the wait
        WAITBAR_4;                     // tile qt landed; qt+1 in flight
        COMPUTE_Q(cur, qt);
        BAR_ONLY;                      // Qs[cur] reads done -> reusable
    }
    WAITBAR_0;                         // peeled last tile (3) in buf 1
    COMPUTE_Q(1, 3);

#pragma unroll
    for (int ks = 0; ks < 2; ks++) {
        float v = cs[ks] + __shfl_xor(cs[ks], 32);
        if (lane < 32)
            atomicAdd(&csum[bh * 2048 + k0 + ks * 32 + lane], v);
    }
}

// ---------------- launch ----------------

extern "C" void kernel_launch(void* const* d_in, const int* in_sizes, int n_in,
                              void* d_out, int out_size, void* d_ws, size_t ws_size,
                              hipStream_t stream) {
    const float* x    = (const float*)d_in[0];   // [2,2048,1024]
    const float* wqkv = (const float*)d_in[1];   // [1024,3072]
    const float* wo   = (const float*)d_in[2];   // [1024,1024]
    float* out = (float*)d_out;                  // [2,2048,1024] fp32
    char* ws = (char*)d_ws;

    u16* xb      = (u16*)(ws);                   // [4096][1024] bf16 (dead after gemm_qkv)
    u16* wqkvT   = (u16*)(ws + 8388608);         // [3072][1024] bf16
    u16* woT     = (u16*)(ws + 14680064);        // [1024][1024] bf16
    u16* qb      = (u16*)(ws + 16777216);        // [32][2048][64] bf16
    u16* kb      = (u16*)(ws + 25165824);
    u16* vb      = (u16*)(ws + 33554432);
    // lp aliases xb (dead after gemm_qkv); csum lives in the free high region
    float* lp    = (float*)(ws);                 // [4][32][2048]
    float* csum  = (float*)(ws + 42467328);      // [32][2048] summed colsum

    prep<<<8192, 256, 0, stream>>>(x, xb, wqkv, wqkvT, wo, woT);
    gemm_qkv<<<768, 256, 0, stream>>>(xb, wqkvT, qb, kb, vb);
    attn_pass1<<<1024, 256, 0, stream>>>(qb, kb, lp, csum);
    attn_pass2<<<1024, 256, 0, stream>>>(qb, kb, lp, csum);
    gemm_out<<<dim3(8, 64), 256, 0, stream>>>(vb, csum, woT, out);
}